// Round 6
// baseline (81709.613 us; speedup 1.0000x reference)
//
#include <hip/hip_runtime.h>
#include <hip/hip_cooperative_groups.h>

namespace cg = cooperative_groups;

#define TSTEP 128
#define LATD 256

// ---------------------------------------------------------------------------
// Persistent cooperative kernel, fp32. Grid 1024 x 256 (4 blocks/CU, 16
// waves/CU). R5 learning: phases are load-LATENCY-chain bound (not barrier
// bound): unroll-4 => K/4 serial waitcnt windows x ~700cyc. Fix: K<=256 per
// block (Ksplit), unroll 8, 4x TLP. 8 phases/step, hierarchical barrier.
// Folds (validated R3-R5):
//   Wvo = Wv@Wo ; Wvoih = Wvo@Wih0 ; bfold = (bv@Wo+bo)@Wih0 + bih0
//   WhW1 = Wh@w1 ; bhw1 = bh@w1 + b1
// ---------------------------------------------------------------------------

struct P {
  const float *z, *w1, *b1, *w2, *b2, *Wv, *bv, *Wo, *bo;
  const float *Wih0, *Whh0, *bih0, *bhh0, *Wih1, *Whh1, *bih1, *bhh1, *Wh, *bh;
  float *out;
  float *Wvoih, *WhW1, *part, *t1, *gin, *h1, *h2, *bvo, *bfold, *bhw1;
  unsigned *bar;  // [0..255] 16 leaf counters (stride 16), [256] root, [288] flag
};

// Hierarchical grid barrier: 1024 arrivals -> 16 padded leaf counters ->
// root -> epoch flag. __threadfence before arrival (release: wbl2) and after
// detection (acquire: inv) — same semantics as R5's proven barrier.
__device__ __forceinline__ void gbar(unsigned* __restrict__ bar, unsigned& ep) {
  __syncthreads();
  ++ep;
  if (threadIdx.x == 0) {
    __threadfence();
    unsigned* leaf = bar + (blockIdx.x & 15u) * 16u;
    unsigned a = atomicAdd(leaf, 1u);
    if (a == ep * 64u - 1u) {              // last arrival of this leaf
      unsigned r = atomicAdd(bar + 256, 1u);
      if (r == ep * 16u - 1u) {            // last leaf
        __hip_atomic_store(bar + 288, ep, __ATOMIC_RELEASE, __HIP_MEMORY_SCOPE_AGENT);
      }
    }
    while (__hip_atomic_load(bar + 288, __ATOMIC_RELAXED, __HIP_MEMORY_SCOPE_AGENT) < ep)
      __builtin_amdgcn_s_sleep(2);
    __threadfence();
  }
  __syncthreads();
}

// ---- prologue helpers (256-thread variants of R3-R5 verified code) --------
// C[rows x N] = A[rows x J] @ B[J x N]; 2 rows/block, blocks [blk0, blk0+rows/2)
template <int J, int N, int CPT>
__device__ void matmat(const float* __restrict__ A, const float* __restrict__ B,
                       float* __restrict__ C, int blk0, int rows) {
  int b = (int)blockIdx.x - blk0;
  if (b < 0 || b >= rows / 2) return;
  int r = b * 2 + ((int)threadIdx.x >> 7);
  int c0 = threadIdx.x & 127;
  float acc[CPT];
#pragma unroll
  for (int i = 0; i < CPT; ++i) acc[i] = 0.f;
  const float* ar = A + (size_t)r * J;
#pragma unroll 2
  for (int j = 0; j < J; ++j) {
    float av = ar[j];
    const float* br = B + (size_t)j * N + c0;
#pragma unroll
    for (int i = 0; i < CPT; ++i) acc[i] = fmaf(av, br[i * 128], acc[i]);
  }
  float* cr = C + (size_t)r * N + c0;
#pragma unroll
  for (int i = 0; i < CPT; ++i) cr[i * 128] = acc[i];
}

__device__ void vecmat(const float* __restrict__ v, const float* __restrict__ M,
                       const float* __restrict__ badd, float* __restrict__ outv,
                       int J, int N, int blk0, int nblk) {
  int b = (int)blockIdx.x;
  if (b < blk0 || b >= blk0 + nblk) return;
  int gid = (b - blk0) * 256 + threadIdx.x;
  if (gid >= N) return;
  float acc = 0.f;
#pragma unroll 4
  for (int j = 0; j < J; ++j) acc = fmaf(v[j], M[(size_t)j * N + gid], acc);
  outv[gid] = acc + badd[gid];
}

// Prologue GEMV: C_T[c][m] = act(A_T @ W[:,c] + bias[c]), N=1024, blocks 0..255
__device__ void gemv_pro(const float* __restrict__ act, const float* __restrict__ W,
                         const float* __restrict__ bias, int K, int relu,
                         float* __restrict__ o1, float* __restrict__ o2,
                         float* __restrict__ o3) {
  if (blockIdx.x >= 256) return;
  int wv = threadIdx.x >> 6, m = threadIdx.x & 63;
  int c = blockIdx.x * 4 + wv;
  float acc = 0.f;
#pragma unroll 8
  for (int k = 0; k < K; ++k) acc = fmaf(act[k * 64 + m], W[(size_t)k * 1024 + c], acc);
  float v = acc + bias[c];
  if (relu) v = fmaxf(v, 0.f);
  o1[c * 64 + m] = v;
  if (o2) o2[c * 64 + m] = v;
  if (o3) o3[c * 64 + m] = v;
}

// ---- main-loop mm tile: 64 cols (lane=col, coalesced) x 32 m x 256 K ------
// unroll 8: 8 weight loads + 16 act float4 loads in flight per waitcnt window
__device__ __forceinline__ void mm_tile(const float* __restrict__ W, int ldw,
                                        const float* __restrict__ act,
                                        int c0, int k0, int mh, float acc[8]) {
  const int lane = threadIdx.x & 63;
  const int m0 = mh * 32 + (threadIdx.x >> 6) * 8;
  const float* wp = W + (size_t)k0 * ldw + c0 + lane;
  const float* ap = act + (size_t)k0 * 64 + m0;
#pragma unroll 8
  for (int k = 0; k < 256; ++k) {
    float wv = wp[(size_t)k * ldw];
    float4 a0 = *(const float4*)(ap + k * 64);
    float4 a1 = *(const float4*)(ap + k * 64 + 4);
    acc[0] = fmaf(wv, a0.x, acc[0]); acc[1] = fmaf(wv, a0.y, acc[1]);
    acc[2] = fmaf(wv, a0.z, acc[2]); acc[3] = fmaf(wv, a0.w, acc[3]);
    acc[4] = fmaf(wv, a1.x, acc[4]); acc[5] = fmaf(wv, a1.y, acc[5]);
    acc[6] = fmaf(wv, a1.z, acc[6]); acc[7] = fmaf(wv, a1.w, acc[7]);
  }
}

__device__ __forceinline__ void st_part(float* __restrict__ base, int col, int mh,
                                        const float acc[8]) {
  const int m0 = mh * 32 + (threadIdx.x >> 6) * 8;
  float* pp = base + (size_t)col * 64 + m0;
  *(float4*)pp = make_float4(acc[0], acc[1], acc[2], acc[3]);
  *(float4*)(pp + 4) = make_float4(acc[4], acc[5], acc[6], acc[7]);
}

// GRU matmul: 768 blocks. cgrp = b>>4 (48 x 64 cols), ksl = (b&15)>>1 (8 x 256
// virtual-K: slices 0-3 = x@Wx, 4-7 = h@Wh), mh = b&1 (m half).
__device__ void gru_mm(const float* __restrict__ Wx, const float* __restrict__ xT,
                       const float* __restrict__ Wh_, const float* __restrict__ hT,
                       float* __restrict__ part) {
  int b = blockIdx.x;
  if (b >= 768) return;
  int cgp = b >> 4, r = b & 15, ksl = r >> 1, mh = r & 1;
  int c0 = cgp * 64;
  float acc[8] = {0.f, 0.f, 0.f, 0.f, 0.f, 0.f, 0.f, 0.f};
  if (ksl < 4) mm_tile(Wx, 3072, xT, c0, ksl * 256, mh, acc);
  else         mm_tile(Wh_, 3072, hT, c0, (ksl - 4) * 256, mh, acc);
  st_part(part + (size_t)ksl * 3072 * 64, c0 + (threadIdx.x & 63), mh, acc);
}

// GRU combine: gates + in-place h update. 128 blocks x 256 thr x 2 elems.
__device__ void gru_comb(const float* __restrict__ part, const float* __restrict__ bx,
                         const float* __restrict__ bm, float* __restrict__ h) {
  int b = blockIdx.x;
  if (b >= 128) return;
#pragma unroll
  for (int e = 0; e < 2; ++e) {
    int idx = b * 512 + e * 256 + threadIdx.x;
    int c = idx >> 6, m = idx & 63;
    float ra = 0.f, za = 0.f, ia = 0.f, na = 0.f;
#pragma unroll
    for (int s = 0; s < 8; ++s) {
      const float* ps = part + (size_t)s * 3072 * 64;
      ra += ps[(size_t)c * 64 + m];
      za += ps[(size_t)(1024 + c) * 64 + m];
      float nv = ps[(size_t)(2048 + c) * 64 + m];
      if (s < 4) ia += nv; else na += nv;
    }
    float rr = 1.f / (1.f + expf(-(ra + bx[c] + bm[c])));
    float zg = 1.f / (1.f + expf(-(za + bx[1024 + c] + bm[1024 + c])));
    float nn = tanhf(ia + bx[2048 + c] + rr * (na + bm[2048 + c]));
    h[(size_t)c * 64 + m] = (1.f - zg) * nn + zg * h[(size_t)c * 64 + m];
  }
}

__global__ __launch_bounds__(256, 4) void persist(P p) {
  cg::grid_group grid = cg::this_grid();
  unsigned ep = 0;
  float* t1part = p.part;                 // 4 x 1024 x 64
  float* nzpart = p.part + 262144;        // 4 x 256 x 64

  // ---- barrier init + one slow cg sync ----
  if (blockIdx.x == 0) { p.bar[threadIdx.x] = 0u; p.bar[threadIdx.x + 256] = 0u; }
  grid.sync();

  // ---- prologue: 4 fast barriers ----
  if (blockIdx.x < 64) {                  // z transpose -> stash in h1 region
    int i = blockIdx.x * 256 + threadIdx.x;
    int m = i >> 8, l = i & 255;
    p.h1[l * 64 + m] = p.z[i];
  }
  matmat<1024, 1024, 8>(p.Wv, p.Wo, p.part, 0, 1024);        // Wvo -> part
  vecmat(p.bh, p.w1, p.b1, p.bhw1, 256, 1024, 512, 4);
  vecmat(p.bv, p.Wo, p.bo, p.bvo, 1024, 1024, 516, 4);
  gbar(p.bar, ep);
  matmat<1024, 3072, 24>(p.part, p.Wih0, p.Wvoih, 0, 1024);  // Wvoih = Wvo@Wih0
  matmat<256, 1024, 8>(p.Wh, p.w1, p.WhW1, 512, 1024);       // WhW1 = Wh@w1
  vecmat(p.bvo, p.Wih0, p.bih0, p.bfold, 1024, 3072, 0, 12); // overlaps matmat blocks: ok
  gbar(p.bar, ep);
  gemv_pro(p.h1, p.w1, p.b1, 256, 1, p.t1, nullptr, nullptr);      // relu(z@w1+b1)
  gbar(p.bar, ep);
  gemv_pro(p.t1, p.w2, p.b2, 1024, 0, p.h1, p.h2, p.gin);          // h0p -> h1,h2,gin
  gbar(p.bar, ep);

  // ---- time loop: 8 phases/step ----
  for (int t = 0; t < TSTEP; ++t) {
    gru_mm(p.Wvoih, p.gin, p.Whh0, p.h1, p.part);            // P1
    gbar(p.bar, ep);
    gru_comb(p.part, p.bfold, p.bhh0, p.h1);                 // P2
    gbar(p.bar, ep);
    gru_mm(p.Wih1, p.h1, p.Whh1, p.h2, p.part);              // P3
    gbar(p.bar, ep);
    gru_comb(p.part, p.bih1, p.bhh1, p.h2);                  // P4
    gbar(p.bar, ep);
    {                                                        // P5: t1/nz partials
      int b = blockIdx.x;
      if (b < 128) {
        int cgp = b >> 3, r = b & 7, ksl = r >> 1, mh = r & 1;
        float acc[8] = {0.f, 0.f, 0.f, 0.f, 0.f, 0.f, 0.f, 0.f};
        mm_tile(p.WhW1, 1024, p.h2, cgp * 64, ksl * 256, mh, acc);
        st_part(t1part + (size_t)ksl * 1024 * 64, cgp * 64 + (threadIdx.x & 63), mh, acc);
      } else if (b < 160) {
        int rel = b - 128;
        int cgp = rel >> 3, r = rel & 7, ksl = r >> 1, mh = r & 1;
        float acc[8] = {0.f, 0.f, 0.f, 0.f, 0.f, 0.f, 0.f, 0.f};
        mm_tile(p.Wh, 256, p.h2, cgp * 64, ksl * 256, mh, acc);
        st_part(nzpart + (size_t)ksl * 256 * 64, cgp * 64 + (threadIdx.x & 63), mh, acc);
      }
    }
    gbar(p.bar, ep);
    {                                                        // P6: reduce -> t1, out
      int b = blockIdx.x;
      if (b < 128) {
#pragma unroll
        for (int e = 0; e < 2; ++e) {
          int idx = b * 512 + e * 256 + threadIdx.x;
          int c = idx >> 6, m = idx & 63;
          float s = t1part[(size_t)c * 64 + m] + t1part[(size_t)(1024 + c) * 64 + m] +
                    t1part[(size_t)(2048 + c) * 64 + m] + t1part[(size_t)(3072 + c) * 64 + m];
          p.t1[(size_t)c * 64 + m] = fmaxf(s + p.bhw1[c], 0.f);
        }
      } else if (b < 160) {
        int rel = b - 128;
#pragma unroll
        for (int e = 0; e < 2; ++e) {
          int idx = rel * 512 + e * 256 + threadIdx.x;
          int c = idx >> 6, m = idx & 63;
          float s = nzpart[(size_t)c * 64 + m] + nzpart[(size_t)(256 + c) * 64 + m] +
                    nzpart[(size_t)(512 + c) * 64 + m] + nzpart[(size_t)(768 + c) * 64 + m];
          p.out[(size_t)(m * TSTEP + t) * LATD + c] = s + p.bh[c];
        }
      }
    }
    gbar(p.bar, ep);
    {                                                        // P7: gin partials
      int b = blockIdx.x;
      if (b < 128) {
        int cgp = b >> 3, r = b & 7, ksl = r >> 1, mh = r & 1;
        float acc[8] = {0.f, 0.f, 0.f, 0.f, 0.f, 0.f, 0.f, 0.f};
        mm_tile(p.w2, 1024, p.t1, cgp * 64, ksl * 256, mh, acc);
        st_part(t1part + (size_t)ksl * 1024 * 64, cgp * 64 + (threadIdx.x & 63), mh, acc);
      }
    }
    gbar(p.bar, ep);
    {                                                        // P8: reduce -> gin
      int b = blockIdx.x;
      if (b < 128) {
#pragma unroll
        for (int e = 0; e < 2; ++e) {
          int idx = b * 512 + e * 256 + threadIdx.x;
          int c = idx >> 6, m = idx & 63;
          float s = t1part[(size_t)c * 64 + m] + t1part[(size_t)(1024 + c) * 64 + m] +
                    t1part[(size_t)(2048 + c) * 64 + m] + t1part[(size_t)(3072 + c) * 64 + m];
          p.gin[(size_t)c * 64 + m] = fmaxf(s + p.b2[c], 0.f);
        }
      }
    }
    gbar(p.bar, ep);
  }
}

// ---------------------------------------------------------------------------
// Fallback path (round-2 verified multi-kernel).
// ---------------------------------------------------------------------------
__global__ void fb_transpose(const float* __restrict__ z, float* __restrict__ zT) {
  int i = blockIdx.x * 256 + threadIdx.x;
  int m = i >> 8, l = i & 255;
  zT[l * 64 + m] = z[i];
}
__global__ void fb_copy2(const float* __restrict__ s, float* __restrict__ d1,
                         float* __restrict__ d2) {
  int i = blockIdx.x * 256 + threadIdx.x;
  float v = s[i]; d1[i] = v; d2[i] = v;
}
template <int ACT>
__global__ void fb_gemm(const float* __restrict__ A_T, const float* __restrict__ W,
                        const float* __restrict__ bias, float* __restrict__ C_T,
                        int K, int N, float* __restrict__ outp, int tstep) {
  const int m = threadIdx.x & 63;
  const int wv = threadIdx.x >> 6;
  const int c = blockIdx.x * 4 + wv;
  float acc0 = 0.f, acc1 = 0.f;
  const float* ap = A_T + m;
  const float* wp = W + c;
#pragma unroll 4
  for (int k = 0; k + 1 < K; k += 2) {
    acc0 = fmaf(ap[k * 64], wp[(size_t)k * N], acc0);
    acc1 = fmaf(ap[(k + 1) * 64], wp[(size_t)(k + 1) * N], acc1);
  }
  float v0 = acc0 + acc1 + bias[c];
  if (ACT) v0 = fmaxf(v0, 0.f);
  C_T[c * 64 + m] = v0;
  if (outp != nullptr) outp[(size_t)(m * TSTEP + tstep) * LATD + c] = v0;
}
__global__ void fb_gru(const float* __restrict__ xT, const float* __restrict__ hT,
                       const float* __restrict__ Wih, const float* __restrict__ Whh,
                       const float* __restrict__ bih, const float* __restrict__ bhh,
                       float* __restrict__ hnT) {
  const int m = threadIdx.x & 63;
  const int wv = threadIdx.x >> 6;
  const int c = blockIdx.x * 4 + wv;
  float racc = 0, zacc = 0, iacc = 0, nacc = 0;
  const float* xp = xT + m;
  const float* hp = hT + m;
  const float* wi = Wih + c;
  const float* wh = Whh + c;
#pragma unroll 2
  for (int k = 0; k < 1024; ++k) {
    float a = xp[k * 64];
    float h = hp[k * 64];
    const float* wik = wi + (size_t)k * 3072;
    const float* whk = wh + (size_t)k * 3072;
    racc = fmaf(a, wik[0], racc); racc = fmaf(h, whk[0], racc);
    zacc = fmaf(a, wik[1024], zacc); zacc = fmaf(h, whk[1024], zacc);
    iacc = fmaf(a, wik[2048], iacc);
    nacc = fmaf(h, whk[2048], nacc);
  }
  float r = 1.f / (1.f + expf(-(racc + bih[c] + bhh[c])));
  float zg = 1.f / (1.f + expf(-(zacc + bih[1024 + c] + bhh[1024 + c])));
  float nn = tanhf(iacc + bih[2048 + c] + r * (nacc + bhh[2048 + c]));
  hnT[c * 64 + m] = (1.f - zg) * nn + zg * hT[c * 64 + m];
}

extern "C" void kernel_launch(void* const* d_in, const int* in_sizes, int n_in,
                              void* d_out, int out_size, void* d_ws, size_t ws_size,
                              hipStream_t stream) {
  const float* z_start = (const float*)d_in[0];
  const float* w1 = (const float*)d_in[2];
  const float* b1 = (const float*)d_in[3];
  const float* w2 = (const float*)d_in[4];
  const float* b2 = (const float*)d_in[5];
  const float* Wv = (const float*)d_in[10];
  const float* bv = (const float*)d_in[11];
  const float* Wo = (const float*)d_in[12];
  const float* bo = (const float*)d_in[13];
  const float* Wih0 = (const float*)d_in[14];
  const float* Whh0 = (const float*)d_in[15];
  const float* bih0 = (const float*)d_in[16];
  const float* bhh0 = (const float*)d_in[17];
  const float* Wih1 = (const float*)d_in[18];
  const float* Whh1 = (const float*)d_in[19];
  const float* bih1 = (const float*)d_in[20];
  const float* bhh1 = (const float*)d_in[21];
  const float* Wh = (const float*)d_in[22];
  const float* bh = (const float*)d_in[23];
  float* out = (float*)d_out;
  float* ws = (float*)d_ws;

  // floats: Wvoih 3145728 + WhW1 1048576 + part 1572864 + t1/gin/h1/h2 4x65536
  //         + bvo 1024 + bfold 3072 + bhw1 1024 + bar 512 = 6034944 (~24.1 MB)
  const size_t need = (size_t)6034944 * 4;
  if (ws_size >= need) {
    P p;
    p.z = z_start; p.w1 = w1; p.b1 = b1; p.w2 = w2; p.b2 = b2;
    p.Wv = Wv; p.bv = bv; p.Wo = Wo; p.bo = bo;
    p.Wih0 = Wih0; p.Whh0 = Whh0; p.bih0 = bih0; p.bhh0 = bhh0;
    p.Wih1 = Wih1; p.Whh1 = Whh1; p.bih1 = bih1; p.bhh1 = bhh1;
    p.Wh = Wh; p.bh = bh; p.out = out;
    float* q = ws;
    p.Wvoih = q; q += 3145728;
    p.WhW1 = q; q += 1048576;
    p.part = q; q += 1572864;   // Wvo in prologue; GRU/t1/nz/gin partials in loop
    p.t1 = q; q += 65536;
    p.gin = q; q += 65536;
    p.h1 = q; q += 65536;       // also holds zT during prologue
    p.h2 = q; q += 65536;
    p.bvo = q; q += 1024;
    p.bfold = q; q += 3072;
    p.bhw1 = q; q += 1024;
    p.bar = (unsigned*)q; q += 512;
    void* args[] = { &p };
    hipError_t e = hipLaunchCooperativeKernel((const void*)persist, dim3(1024),
                                              dim3(256), args, 0, stream);
    if (e == hipSuccess) return;
  }

  // -------- fallback: verified round-2 path --------
  float* zsT = ws;
  float* vT = zsT + 16384;
  float* xaT = vT + 65536;
  float* t1T = xaT + 65536;
  float* ginT = t1T + 65536;
  float* nzT = ginT + 65536;
  float* h1T = nzT + 16384;
  float* h2T = h1T + 2 * 65536;

  fb_transpose<<<64, 256, 0, stream>>>(z_start, zsT);
  fb_gemm<1><<<256, 256, 0, stream>>>(zsT, w1, b1, t1T, 256, 1024, nullptr, 0);
  fb_gemm<0><<<256, 256, 0, stream>>>(t1T, w2, b2, h1T, 1024, 1024, nullptr, 0);
  fb_copy2<<<256, 256, 0, stream>>>(h1T, h2T, ginT);
  for (int t = 0; t < TSTEP; ++t) {
    float* h1p = h1T + (t & 1) * 65536;
    float* h1n = h1T + ((t + 1) & 1) * 65536;
    float* h2p = h2T + (t & 1) * 65536;
    float* h2n = h2T + ((t + 1) & 1) * 65536;
    fb_gemm<0><<<256, 256, 0, stream>>>(ginT, Wv, bv, vT, 1024, 1024, nullptr, 0);
    fb_gemm<0><<<256, 256, 0, stream>>>(vT, Wo, bo, xaT, 1024, 1024, nullptr, 0);
    fb_gru<<<256, 256, 0, stream>>>(xaT, h1p, Wih0, Whh0, bih0, bhh0, h1n);
    fb_gru<<<256, 256, 0, stream>>>(h1n, h2p, Wih1, Whh1, bih1, bhh1, h2n);
    fb_gemm<0><<<64, 256, 0, stream>>>(h2n, Wh, bh, nzT, 1024, 256, out, t);
    fb_gemm<1><<<256, 256, 0, stream>>>(nzT, w1, b1, t1T, 256, 1024, nullptr, 0);
    fb_gemm<1><<<256, 256, 0, stream>>>(t1T, w2, b2, ginT, 1024, 1024, nullptr, 0);
  }
}

// Round 7
// 19272.385 us; speedup vs baseline: 4.2397x; 4.2397x over previous
//
#include <hip/hip_runtime.h>
#include <hip/hip_cooperative_groups.h>

namespace cg = cooperative_groups;

#define TSTEP 128
#define LATD 256

// ---------------------------------------------------------------------------
// R7: fence-free persistent kernel. 256 blocks x 512 threads (1 block/CU).
// Key change vs R4-R6: ZERO __threadfence in the time loop. Evidence: ~80us
// per phase+barrier constant across all prior designs = per-leader L2
// wbl2/inv storms. Now:
//  - acts/partials/flag: sc1 per-access coherent atomics (agent scope) —
//    cross-XCD visibility proven by R5/R6's own working barriers.
//  - weights: normal cached loads; L2 never invalidated -> resident all run.
//  - barrier: s_waitcnt(0) + syncthreads + atomicAdd + relaxed poll. No
//    cache maintenance.
// Folds (verified R3-R6): Wvoih = (Wv@Wo)@Wih0, bfold = (bv@Wo+bo)@Wih0+bih0,
// WhW1 = Wh@w1, bhw1 = bh@w1+b1. Step = 8 phases:
// gru0mm / gru0comb / gru1mm / gru1comb / p5mm(t1,nz) / p5comb / p6mm(gin) / p6comb
// ---------------------------------------------------------------------------

struct P {
  const float *z, *w1, *b1, *w2, *b2, *Wv, *bv, *Wo, *bo;
  const float *Wih0, *Whh0, *bih0, *bhh0, *Wih1, *Whh1, *bih1, *bhh1, *Wh, *bh;
  float *out;
  float *Wvoih, *WhW1, *part, *gin, *h1, *h2, *t1, *bvo, *bfold, *bhw1;
  unsigned *bar;   // [0]=count, [32]=flag (separate lines)
};

__device__ __forceinline__ float ald(const float* p) {
  return __hip_atomic_load((float*)p, __ATOMIC_RELAXED, __HIP_MEMORY_SCOPE_AGENT);
}
__device__ __forceinline__ void ast(float* p, float v) {
  __hip_atomic_store(p, v, __ATOMIC_RELAXED, __HIP_MEMORY_SCOPE_AGENT);
}
__device__ __forceinline__ unsigned long long ald64(const unsigned long long* p) {
  return __hip_atomic_load((unsigned long long*)p, __ATOMIC_RELAXED,
                           __HIP_MEMORY_SCOPE_AGENT);
}

// Fence-free grid barrier. Correctness: every thread drains its vmem queue
// (sc1 stores ack from the coherence point) before syncthreads; leader's
// atomicAdd is therefore ordered after all the block's stores are globally
// visible. Readers use sc1 loads (always fetch from coherence point), so no
// L2 invalidate is needed anywhere.
__device__ __forceinline__ void fastbar(unsigned* bar, unsigned& ep) {
  ++ep;
  __atomic_signal_fence(__ATOMIC_SEQ_CST);
  __builtin_amdgcn_s_waitcnt(0);
  __atomic_signal_fence(__ATOMIC_SEQ_CST);
  __syncthreads();
  if (threadIdx.x == 0) {
    unsigned old = atomicAdd(bar, 1u);
    if (old == ep * 256u - 1u)
      __hip_atomic_store(bar + 32, ep, __ATOMIC_RELAXED, __HIP_MEMORY_SCOPE_AGENT);
    while (__hip_atomic_load(bar + 32, __ATOMIC_RELAXED, __HIP_MEMORY_SCOPE_AGENT) < ep)
      __builtin_amdgcn_s_sleep(1);
  }
  __syncthreads();
}

// ---- prologue helpers (R5-verified, 256 blocks x 512 threads) -------------
template <int J, int N, int CPT>
__device__ void matmat(const float* __restrict__ A, const float* __restrict__ B,
                       float* __restrict__ C) {
  const int tid = threadIdx.x;
  const int r = blockIdx.x * 4 + (tid >> 7);
  const int c0 = tid & 127;
  float acc[CPT];
#pragma unroll
  for (int i = 0; i < CPT; ++i) acc[i] = 0.f;
  const float* ar = A + (size_t)r * J;
#pragma unroll 2
  for (int j = 0; j < J; ++j) {
    float av = ar[j];
    const float* br = B + (size_t)j * N + c0;
#pragma unroll
    for (int i = 0; i < CPT; ++i) acc[i] = fmaf(av, br[i * 128], acc[i]);
  }
  float* cr = C + (size_t)r * N + c0;
#pragma unroll
  for (int i = 0; i < CPT; ++i) cr[i * 128] = acc[i];
}

__device__ void vecmat(const float* __restrict__ v, const float* __restrict__ M,
                       const float* __restrict__ badd, float* __restrict__ outv,
                       int J, int N, int blk0, int nblk) {
  int b = (int)blockIdx.x;
  if (b < blk0 || b >= blk0 + nblk) return;
  int gid = (b - blk0) * 512 + threadIdx.x;
  if (gid >= N) return;
  float acc = 0.f;
#pragma unroll 4
  for (int j = 0; j < J; ++j) acc = fmaf(v[j], M[(size_t)j * N + gid], acc);
  outv[gid] = acc + badd[gid];
}

__device__ void gemv1024(const float* __restrict__ A, const float* __restrict__ W,
                         const float* __restrict__ bias, int K, int relu,
                         float* __restrict__ C, float* __restrict__ C2,
                         float* __restrict__ C3, float* red) {
  const int tid = threadIdx.x;
  const int m = tid & 63, w = tid >> 6;
  const int j = w & 3, hh = w >> 2;
  const int c = blockIdx.x * 4 + j;
  const int kh = K >> 1;
  const float* a = A + m + (hh * kh) * 64;
  const float* wp = W + c + (size_t)(hh * kh) * 1024;
  float acc = 0.f;
#pragma unroll 8
  for (int k = 0; k < kh; ++k) acc = fmaf(a[k * 64], wp[(size_t)k * 1024], acc);
  if (hh) red[j * 64 + m] = acc;
  __syncthreads();
  if (!hh) {
    float v = acc + red[j * 64 + m] + bias[c];
    if (relu) v = fmaxf(v, 0.f);
    C[c * 64 + m] = v;
    if (C2) C2[c * 64 + m] = v;
    if (C3) C3[c * 64 + m] = v;
  }
  __syncthreads();
}

// ---- GRU matmul phase: block = (g: 64 groups x 48 cols, s: 4 K-slices) ----
// s<2: x-part rows s*512 of actx vs Wx; s>=2: h-part rows (s-2)*512 vs Whm.
// Acts staged via sc1 u64 loads; weight tiles via cached loads. 8 chunks of
// 64 K-rows, double-buffered LDS. Wave w computes 6 cols (slot w*8..w*8+5).
__device__ __forceinline__ void gru_mm(const float* __restrict__ Wx,
                                       const float* __restrict__ actx,
                                       const float* __restrict__ Whm,
                                       const float* __restrict__ acth,
                                       float* __restrict__ part,
                                       float* __restrict__ sm) {
  float* sa = sm;          // [2][4096] acts [k][m]
  float* sw = sm + 8192;   // [2][4096] weights [k][wave*8+j]
  const int tid = threadIdx.x;
  const int lane = tid & 63, wv = tid >> 6;
  const int bid = blockIdx.x;
  const int g = bid >> 2, s = bid & 3;
  const int c0 = g * 48;
  const float* W = (s < 2 ? Wx : Whm) + (size_t)((s & 1) * 512) * 3072;
  const float* A = (s < 2 ? actx : acth) + (s & 1) * 512 * 64;
  const int wr = tid >> 3, ws8 = tid & 7;
  float acc[6] = {0.f, 0.f, 0.f, 0.f, 0.f, 0.f};
  unsigned long long av[4];
  float2 wl[3];
  {  // stage chunk 0 into buf 0
    const unsigned long long* Ab = (const unsigned long long*)A;
#pragma unroll
    for (int i = 0; i < 4; ++i) av[i] = ald64(Ab + tid + i * 512);
    const float* Wr = W + (size_t)wr * 3072 + c0 + ws8 * 6;
    wl[0] = *(const float2*)Wr; wl[1] = *(const float2*)(Wr + 2);
    wl[2] = *(const float2*)(Wr + 4);
#pragma unroll
    for (int i = 0; i < 4; ++i) {
      int jj = tid + i * 512;
      *(unsigned long long*)(sa + ((jj >> 5) << 6) + ((jj & 31) << 1)) = av[i];
    }
    float* swr = sw + wr * 64 + ws8 * 8;
    *(float2*)swr = wl[0]; *(float2*)(swr + 2) = wl[1]; *(float2*)(swr + 4) = wl[2];
  }
  for (int ch = 0; ch < 8; ++ch) {
    const int buf = ch & 1;
    __syncthreads();
    if (ch < 7) {  // prefetch chunk ch+1
      const unsigned long long* Ab = (const unsigned long long*)(A + (ch + 1) * 4096);
#pragma unroll
      for (int i = 0; i < 4; ++i) av[i] = ald64(Ab + tid + i * 512);
      const float* Wr = W + (size_t)((ch + 1) * 64 + wr) * 3072 + c0 + ws8 * 6;
      wl[0] = *(const float2*)Wr; wl[1] = *(const float2*)(Wr + 2);
      wl[2] = *(const float2*)(Wr + 4);
    }
    const float* ap = sa + buf * 4096 + lane;
    const float* wp = sw + buf * 4096 + wv * 8;
#pragma unroll 16
    for (int k = 0; k < 64; ++k) {
      float a = ap[k * 64];
      float4 w4 = *(const float4*)(wp + k * 64);
      float2 w2v = *(const float2*)(wp + k * 64 + 4);
      acc[0] = fmaf(a, w4.x, acc[0]); acc[1] = fmaf(a, w4.y, acc[1]);
      acc[2] = fmaf(a, w4.z, acc[2]); acc[3] = fmaf(a, w4.w, acc[3]);
      acc[4] = fmaf(a, w2v.x, acc[4]); acc[5] = fmaf(a, w2v.y, acc[5]);
    }
    if (ch < 7) {
      const int nb = buf ^ 1;
#pragma unroll
      for (int i = 0; i < 4; ++i) {
        int jj = tid + i * 512;
        *(unsigned long long*)(sa + nb * 4096 + ((jj >> 5) << 6) + ((jj & 31) << 1)) = av[i];
      }
      float* swr = sw + nb * 4096 + wr * 64 + ws8 * 8;
      *(float2*)swr = wl[0]; *(float2*)(swr + 2) = wl[1]; *(float2*)(swr + 4) = wl[2];
    }
  }
  float* pb = part + ((size_t)s * 3072 + c0 + wv * 6) * 64 + lane;
#pragma unroll
  for (int j = 0; j < 6; ++j) ast(pb + j * 64, acc[j]);
}

// GRU combine: h-col c = bid*4 + tid>>6 (tid<256), gates from 4 K-slices.
__device__ __forceinline__ void gru_comb(const float* __restrict__ part,
                                         const float* __restrict__ bx,
                                         const float* __restrict__ bm,
                                         float* __restrict__ h) {
  const int tid = threadIdx.x, bid = blockIdx.x;
  if (tid >= 256) return;
  const int c = bid * 4 + (tid >> 6), m = tid & 63;
  float ra = 0.f, za = 0.f, ia = 0.f, na = 0.f;
#pragma unroll
  for (int s = 0; s < 4; ++s) {
    const float* ps = part + (size_t)s * 3072 * 64;
    ra += ald(ps + (size_t)c * 64 + m);
    za += ald(ps + (size_t)(1024 + c) * 64 + m);
    float nv = ald(ps + (size_t)(2048 + c) * 64 + m);
    if (s < 2) ia += nv; else na += nv;
  }
  float r  = 1.f / (1.f + expf(-(ra + bx[c] + bm[c])));
  float zg = 1.f / (1.f + expf(-(za + bx[1024 + c] + bm[1024 + c])));
  float nn = tanhf(ia + bx[2048 + c] + r * (na + bm[2048 + c]));
  float hp = ald(h + (size_t)c * 64 + m);
  ast(h + (size_t)c * 64 + m, (1.f - zg) * nn + zg * hp);
}

// P5: 1280 cols (1024 WhW1 + 256 Wh), block = (g:128 x 10 cols, s:2 x 512K).
__device__ __forceinline__ void p5_mm(const float* __restrict__ WhW1,
                                      const float* __restrict__ Wh,
                                      const float* __restrict__ h2,
                                      float* __restrict__ part,
                                      float* __restrict__ sm) {
  float* sa = sm;
  float* sw = sm + 8192;   // [2][1024] tile [k][16]
  const int tid = threadIdx.x;
  const int lane = tid & 63, wv = tid >> 6;
  const int bid = blockIdx.x;
  const int g = bid >> 1, s = bid & 1;
  const int c0 = g * 10;
  const float* A = h2 + s * 512 * 64;
  const int wr = tid >> 3, ws8 = tid & 7;
  float acc[2] = {0.f, 0.f};
  unsigned long long av[4];
  float wl0, wl1;
#define P5W(ch, slot) \
  ((c0 + (slot)) < 1024 \
     ? WhW1[(size_t)(s * 512 + (ch) * 64 + wr) * 1024 + c0 + (slot)] \
     : Wh[(size_t)(s * 512 + (ch) * 64 + wr) * 256 + (c0 + (slot) - 1024)])
  {
    const unsigned long long* Ab = (const unsigned long long*)A;
#pragma unroll
    for (int i = 0; i < 4; ++i) av[i] = ald64(Ab + tid + i * 512);
    wl0 = P5W(0, ws8); wl1 = (ws8 < 2) ? P5W(0, 8 + ws8) : 0.f;
#pragma unroll
    for (int i = 0; i < 4; ++i) {
      int jj = tid + i * 512;
      *(unsigned long long*)(sa + ((jj >> 5) << 6) + ((jj & 31) << 1)) = av[i];
    }
    sw[wr * 16 + ws8] = wl0; if (ws8 < 2) sw[wr * 16 + 8 + ws8] = wl1;
  }
  for (int ch = 0; ch < 8; ++ch) {
    const int buf = ch & 1;
    __syncthreads();
    if (ch < 7) {
      const unsigned long long* Ab = (const unsigned long long*)(A + (ch + 1) * 4096);
#pragma unroll
      for (int i = 0; i < 4; ++i) av[i] = ald64(Ab + tid + i * 512);
      wl0 = P5W(ch + 1, ws8); wl1 = (ws8 < 2) ? P5W(ch + 1, 8 + ws8) : 0.f;
    }
    if (wv < 5) {
      const float* ap = sa + buf * 4096 + lane;
      const float* wp = sw + buf * 1024 + 2 * wv;
#pragma unroll 16
      for (int k = 0; k < 64; ++k) {
        float a = ap[k * 64];
        float2 w2v = *(const float2*)(wp + k * 16);
        acc[0] = fmaf(a, w2v.x, acc[0]); acc[1] = fmaf(a, w2v.y, acc[1]);
      }
    }
    if (ch < 7) {
      const int nb = buf ^ 1;
#pragma unroll
      for (int i = 0; i < 4; ++i) {
        int jj = tid + i * 512;
        *(unsigned long long*)(sa + nb * 4096 + ((jj >> 5) << 6) + ((jj & 31) << 1)) = av[i];
      }
      sw[nb * 1024 + wr * 16 + ws8] = wl0;
      if (ws8 < 2) sw[nb * 1024 + wr * 16 + 8 + ws8] = wl1;
    }
  }
#undef P5W
  if (wv < 5) {
    float* pb = part + ((size_t)s * 1280 + c0 + 2 * wv) * 64 + lane;
    ast(pb, acc[0]); ast(pb + 64, acc[1]);
  }
}

// P5 combine: t1 = relu(.+bhw1) (tid<256); out col = bid (tid 256..319).
__device__ __forceinline__ void p5b(const float* __restrict__ part,
                                    const float* __restrict__ bhw1,
                                    const float* __restrict__ bh,
                                    float* __restrict__ t1, float* __restrict__ out,
                                    int t) {
  const int tid = threadIdx.x, bid = blockIdx.x;
  if (tid < 256) {
    const int c = bid * 4 + (tid >> 6), m = tid & 63;
    float v = ald(part + (size_t)c * 64 + m) + ald(part + (size_t)(1280 + c) * 64 + m);
    ast(t1 + (size_t)c * 64 + m, fmaxf(v + bhw1[c], 0.f));
  } else if (tid < 320) {
    const int m = tid - 256, c2 = bid;
    float v = ald(part + (size_t)(1024 + c2) * 64 + m) +
              ald(part + (size_t)(2304 + c2) * 64 + m);
    out[(size_t)(m * TSTEP + t) * LATD + c2] = v + bh[c2];
  }
}

// P6: gin partials; 1024 w2 cols, block = (g:128 x 8 cols, s:2 x 512K).
__device__ __forceinline__ void p6_mm(const float* __restrict__ w2,
                                      const float* __restrict__ t1,
                                      float* __restrict__ part,
                                      float* __restrict__ sm) {
  float* sa = sm;
  float* sw = sm + 8192;   // [2][512] tile [k][8]
  const int tid = threadIdx.x;
  const int lane = tid & 63, wv = tid >> 6;
  const int bid = blockIdx.x;
  const int g = bid >> 1, s = bid & 1;
  const float* A = t1 + s * 512 * 64;
  const int wr = tid >> 3, ws8 = tid & 7;
  float acc = 0.f;
  unsigned long long av[4];
  float wl0;
  {
    const unsigned long long* Ab = (const unsigned long long*)A;
#pragma unroll
    for (int i = 0; i < 4; ++i) av[i] = ald64(Ab + tid + i * 512);
    wl0 = w2[(size_t)(s * 512 + wr) * 1024 + g * 8 + ws8];
#pragma unroll
    for (int i = 0; i < 4; ++i) {
      int jj = tid + i * 512;
      *(unsigned long long*)(sa + ((jj >> 5) << 6) + ((jj & 31) << 1)) = av[i];
    }
    sw[wr * 8 + ws8] = wl0;
  }
  for (int ch = 0; ch < 8; ++ch) {
    const int buf = ch & 1;
    __syncthreads();
    if (ch < 7) {
      const unsigned long long* Ab = (const unsigned long long*)(A + (ch + 1) * 4096);
#pragma unroll
      for (int i = 0; i < 4; ++i) av[i] = ald64(Ab + tid + i * 512);
      wl0 = w2[(size_t)(s * 512 + (ch + 1) * 64 + wr) * 1024 + g * 8 + ws8];
    }
    const float* ap = sa + buf * 4096 + lane;
    const float* wp = sw + buf * 512 + wv;
#pragma unroll 16
    for (int k = 0; k < 64; ++k)
      acc = fmaf(ap[k * 64], wp[k * 8], acc);
    if (ch < 7) {
      const int nb = buf ^ 1;
#pragma unroll
      for (int i = 0; i < 4; ++i) {
        int jj = tid + i * 512;
        *(unsigned long long*)(sa + nb * 4096 + ((jj >> 5) << 6) + ((jj & 31) << 1)) = av[i];
      }
      sw[nb * 512 + wr * 8 + ws8] = wl0;
    }
  }
  ast(part + ((size_t)s * 1024 + g * 8 + wv) * 64 + lane, acc);
}

__device__ __forceinline__ void p6b(const float* __restrict__ part,
                                    const float* __restrict__ b2,
                                    float* __restrict__ gin) {
  const int tid = threadIdx.x, bid = blockIdx.x;
  if (tid >= 256) return;
  const int c = bid * 4 + (tid >> 6), m = tid & 63;
  float v = ald(part + (size_t)c * 64 + m) + ald(part + (size_t)(1024 + c) * 64 + m);
  ast(gin + (size_t)c * 64 + m, fmaxf(v + b2[c], 0.f));
}

__global__ __launch_bounds__(512, 1) void persist(P p) {
  cg::grid_group grid = cg::this_grid();
  __shared__ float sm[16384];   // 64 KB: [acts 2x4096 | weights 2x4096]
  unsigned ep = 0;

  // ---- prologue (4 slow cg syncs; their fences also flush prologue writes,
  //      so loop-side cached weight reads and sc1 act reads start clean) ----
  if (blockIdx.x == 0 && threadIdx.x < 64) p.bar[threadIdx.x] = 0u;
  if (threadIdx.x < 64) {  // z transpose -> h1 region (consumed before overwrite)
    int i = blockIdx.x * 64 + threadIdx.x;
    int m = i >> 8, l = i & 255;
    p.h1[l * 64 + m] = p.z[i];
  }
  matmat<1024, 1024, 8>(p.Wv, p.Wo, p.part);            // Wvo
  vecmat(p.bh, p.w1, p.b1, p.bhw1, 256, 1024, 0, 2);
  vecmat(p.bv, p.Wo, p.bo, p.bvo, 1024, 1024, 2, 2);
  grid.sync();
  matmat<1024, 3072, 24>(p.part, p.Wih0, p.Wvoih);      // Wvoih = Wvo@Wih0
  matmat<256, 1024, 8>(p.Wh, p.w1, p.WhW1);             // WhW1 = Wh@w1
  vecmat(p.bvo, p.Wih0, p.bih0, p.bfold, 1024, 3072, 0, 6);
  grid.sync();
  gemv1024(p.h1, p.w1, p.b1, 256, 1, p.t1, nullptr, nullptr, sm);
  grid.sync();
  gemv1024(p.t1, p.w2, p.b2, 1024, 0, p.h1, p.h2, p.gin, sm);
  grid.sync();

  // ---- time loop: 8 fence-free phases/step ----
  for (int t = 0; t < TSTEP; ++t) {
    gru_mm(p.Wvoih, p.gin, p.Whh0, p.h1, p.part, sm);   fastbar(p.bar, ep);
    gru_comb(p.part, p.bfold, p.bhh0, p.h1);            fastbar(p.bar, ep);
    gru_mm(p.Wih1, p.h1, p.Whh1, p.h2, p.part, sm);     fastbar(p.bar, ep);
    gru_comb(p.part, p.bih1, p.bhh1, p.h2);             fastbar(p.bar, ep);
    p5_mm(p.WhW1, p.Wh, p.h2, p.part, sm);              fastbar(p.bar, ep);
    p5b(p.part, p.bhw1, p.bh, p.t1, p.out, t);          fastbar(p.bar, ep);
    p6_mm(p.w2, p.t1, p.part, sm);                      fastbar(p.bar, ep);
    p6b(p.part, p.b2, p.gin);                           fastbar(p.bar, ep);
  }
}

// ---------------------------------------------------------------------------
// Fallback path (round-2 verified multi-kernel).
// ---------------------------------------------------------------------------
__global__ void fb_transpose(const float* __restrict__ z, float* __restrict__ zT) {
  int i = blockIdx.x * 256 + threadIdx.x;
  int m = i >> 8, l = i & 255;
  zT[l * 64 + m] = z[i];
}
__global__ void fb_copy2(const float* __restrict__ s, float* __restrict__ d1,
                         float* __restrict__ d2) {
  int i = blockIdx.x * 256 + threadIdx.x;
  float v = s[i]; d1[i] = v; d2[i] = v;
}
template <int ACT>
__global__ void fb_gemm(const float* __restrict__ A_T, const float* __restrict__ W,
                        const float* __restrict__ bias, float* __restrict__ C_T,
                        int K, int N, float* __restrict__ outp, int tstep) {
  const int m = threadIdx.x & 63;
  const int wv = threadIdx.x >> 6;
  const int c = blockIdx.x * 4 + wv;
  float acc0 = 0.f, acc1 = 0.f;
  const float* ap = A_T + m;
  const float* wp = W + c;
#pragma unroll 4
  for (int k = 0; k + 1 < K; k += 2) {
    acc0 = fmaf(ap[k * 64], wp[(size_t)k * N], acc0);
    acc1 = fmaf(ap[(k + 1) * 64], wp[(size_t)(k + 1) * N], acc1);
  }
  float v0 = acc0 + acc1 + bias[c];
  if (ACT) v0 = fmaxf(v0, 0.f);
  C_T[c * 64 + m] = v0;
  if (outp != nullptr) outp[(size_t)(m * TSTEP + tstep) * LATD + c] = v0;
}
__global__ void fb_gru(const float* __restrict__ xT, const float* __restrict__ hT,
                       const float* __restrict__ Wih, const float* __restrict__ Whh,
                       const float* __restrict__ bih, const float* __restrict__ bhh,
                       float* __restrict__ hnT) {
  const int m = threadIdx.x & 63;
  const int wv = threadIdx.x >> 6;
  const int c = blockIdx.x * 4 + wv;
  float racc = 0, zacc = 0, iacc = 0, nacc = 0;
  const float* xp = xT + m;
  const float* hp = hT + m;
  const float* wi = Wih + c;
  const float* wh = Whh + c;
#pragma unroll 2
  for (int k = 0; k < 1024; ++k) {
    float a = xp[k * 64];
    float h = hp[k * 64];
    const float* wik = wi + (size_t)k * 3072;
    const float* whk = wh + (size_t)k * 3072;
    racc = fmaf(a, wik[0], racc); racc = fmaf(h, whk[0], racc);
    zacc = fmaf(a, wik[1024], zacc); zacc = fmaf(h, whk[1024], zacc);
    iacc = fmaf(a, wik[2048], iacc);
    nacc = fmaf(h, whk[2048], nacc);
  }
  float r = 1.f / (1.f + expf(-(racc + bih[c] + bhh[c])));
  float zg = 1.f / (1.f + expf(-(zacc + bih[1024 + c] + bhh[1024 + c])));
  float nn = tanhf(iacc + bih[2048 + c] + r * (nacc + bhh[2048 + c]));
  hnT[c * 64 + m] = (1.f - zg) * nn + zg * hT[c * 64 + m];
}

extern "C" void kernel_launch(void* const* d_in, const int* in_sizes, int n_in,
                              void* d_out, int out_size, void* d_ws, size_t ws_size,
                              hipStream_t stream) {
  const float* z_start = (const float*)d_in[0];
  const float* w1 = (const float*)d_in[2];
  const float* b1 = (const float*)d_in[3];
  const float* w2 = (const float*)d_in[4];
  const float* b2 = (const float*)d_in[5];
  const float* Wv = (const float*)d_in[10];
  const float* bv = (const float*)d_in[11];
  const float* Wo = (const float*)d_in[12];
  const float* bo = (const float*)d_in[13];
  const float* Wih0 = (const float*)d_in[14];
  const float* Whh0 = (const float*)d_in[15];
  const float* bih0 = (const float*)d_in[16];
  const float* bhh0 = (const float*)d_in[17];
  const float* Wih1 = (const float*)d_in[18];
  const float* Whh1 = (const float*)d_in[19];
  const float* bih1 = (const float*)d_in[20];
  const float* bhh1 = (const float*)d_in[21];
  const float* Wh = (const float*)d_in[22];
  const float* bh = (const float*)d_in[23];
  float* out = (float*)d_out;
  float* ws = (float*)d_ws;

  // floats: Wvoih 3145728 + WhW1 1048576 + part 1048576 + gin/h1/h2/t1
  //         4x65536 + bvo 1024 + bfold 3072 + bhw1 1024 + bar 64 = 5510208
  const size_t need = (size_t)5510208 * 4;
  if (ws_size >= need) {
    P p;
    p.z = z_start; p.w1 = w1; p.b1 = b1; p.w2 = w2; p.b2 = b2;
    p.Wv = Wv; p.bv = bv; p.Wo = Wo; p.bo = bo;
    p.Wih0 = Wih0; p.Whh0 = Whh0; p.bih0 = bih0; p.bhh0 = bhh0;
    p.Wih1 = Wih1; p.Whh1 = Whh1; p.bih1 = bih1; p.bhh1 = bhh1;
    p.Wh = Wh; p.bh = bh; p.out = out;
    float* q = ws;
    p.Wvoih = q; q += 3145728;
    p.WhW1 = q; q += 1048576;
    p.part = q; q += 1048576;   // Wvo in prologue; phase partials in loop
    p.gin = q; q += 65536;
    p.h1 = q; q += 65536;       // also zT during prologue
    p.h2 = q; q += 65536;
    p.t1 = q; q += 65536;
    p.bvo = q; q += 1024;
    p.bfold = q; q += 3072;
    p.bhw1 = q; q += 1024;
    p.bar = (unsigned*)q; q += 64;
    void* args[] = { &p };
    hipError_t e = hipLaunchCooperativeKernel((const void*)persist, dim3(256),
                                              dim3(512), args, 0, stream);
    if (e == hipSuccess) return;
  }

  // -------- fallback: verified round-2 path --------
  float* zsT = ws;
  float* vT = zsT + 16384;
  float* xaT = vT + 65536;
  float* t1T = xaT + 65536;
  float* ginT = t1T + 65536;
  float* nzT = ginT + 65536;
  float* h1T = nzT + 16384;
  float* h2T = h1T + 2 * 65536;

  fb_transpose<<<64, 256, 0, stream>>>(z_start, zsT);
  fb_gemm<1><<<256, 256, 0, stream>>>(zsT, w1, b1, t1T, 256, 1024, nullptr, 0);
  fb_gemm<0><<<256, 256, 0, stream>>>(t1T, w2, b2, h1T, 1024, 1024, nullptr, 0);
  fb_copy2<<<256, 256, 0, stream>>>(h1T, h2T, ginT);
  for (int t = 0; t < TSTEP; ++t) {
    float* h1p = h1T + (t & 1) * 65536;
    float* h1n = h1T + ((t + 1) & 1) * 65536;
    float* h2p = h2T + (t & 1) * 65536;
    float* h2n = h2T + ((t + 1) & 1) * 65536;
    fb_gemm<0><<<256, 256, 0, stream>>>(ginT, Wv, bv, vT, 1024, 1024, nullptr, 0);
    fb_gemm<0><<<256, 256, 0, stream>>>(vT, Wo, bo, xaT, 1024, 1024, nullptr, 0);
    fb_gru<<<256, 256, 0, stream>>>(xaT, h1p, Wih0, Whh0, bih0, bhh0, h1n);
    fb_gru<<<256, 256, 0, stream>>>(h1n, h2p, Wih1, Whh1, bih1, bhh1, h2n);
    fb_gemm<0><<<64, 256, 0, stream>>>(h2n, Wh, bh, nzT, 1024, 256, out, t);
    fb_gemm<1><<<256, 256, 0, stream>>>(nzT, w1, b1, t1T, 256, 1024, nullptr, 0);
    fb_gemm<1><<<256, 256, 0, stream>>>(t1T, w2, b2, ginT, 1024, 1024, nullptr, 0);
  }
}

// Round 8
// 14608.759 us; speedup vs baseline: 5.5932x; 1.3192x over previous
//
#include <hip/hip_runtime.h>
#include <hip/hip_cooperative_groups.h>

namespace cg = cooperative_groups;

#define TSTEP 128
#define LATD 256

// ---------------------------------------------------------------------------
// R8: fence-free persistent kernel (R7 skeleton) with traffic-tuned tiles.
//  - gru_mm: c_b=96 (12 acc/thread, half-wave col split), K-split 8 -> act
//    amplification 64->32 and 2x FMA per LDS act-issue.
//  - p5/p6: c_b=40/32, K-split 8 -> amplification 128->32.
//  - hierarchical fence-free barrier (16 leaf counters -> root -> flag).
// Cross-block traffic ~142 -> ~84 MB/step. Weights stay L2-resident (no
// cache maintenance anywhere in the loop).
// Folds (verified R3-R7): Wvoih=(Wv@Wo)@Wih0, bfold=(bv@Wo+bo)@Wih0+bih0,
// WhW1=Wh@w1, bhw1=bh@w1+b1. Step = 8 phases.
// ---------------------------------------------------------------------------

struct P {
  const float *z, *w1, *b1, *w2, *b2, *Wv, *bv, *Wo, *bo;
  const float *Wih0, *Whh0, *bih0, *bhh0, *Wih1, *Whh1, *bih1, *bhh1, *Wh, *bh;
  float *out;
  float *Wvoih, *WhW1, *part, *gin, *h1, *h2, *t1, *bvo, *bfold, *bhw1;
  unsigned *bar;   // leaves at i*32 (i<16), root at 512, flag at 544
};

__device__ __forceinline__ float ald(const float* p) {
  return __hip_atomic_load((float*)p, __ATOMIC_RELAXED, __HIP_MEMORY_SCOPE_AGENT);
}
__device__ __forceinline__ void ast(float* p, float v) {
  __hip_atomic_store(p, v, __ATOMIC_RELAXED, __HIP_MEMORY_SCOPE_AGENT);
}
__device__ __forceinline__ unsigned long long ald64(const unsigned long long* p) {
  return __hip_atomic_load((unsigned long long*)p, __ATOMIC_RELAXED,
                           __HIP_MEMORY_SCOPE_AGENT);
}

// Fence-free hierarchical grid barrier (semantics proven in R7; tree cuts
// 256 serialized line-RMWs to 16/line). waitcnt(0) drains sc1 stores before
// arrival; readers use sc1 loads, so no cache maintenance is needed.
__device__ __forceinline__ void fastbar(unsigned* bar, unsigned& ep) {
  ++ep;
  __atomic_signal_fence(__ATOMIC_SEQ_CST);
  __builtin_amdgcn_s_waitcnt(0);
  __atomic_signal_fence(__ATOMIC_SEQ_CST);
  __syncthreads();
  if (threadIdx.x == 0) {
    unsigned* leaf = bar + (blockIdx.x & 15u) * 32u;
    unsigned a = atomicAdd(leaf, 1u);
    if (a == ep * 16u - 1u) {
      unsigned r = atomicAdd(bar + 512, 1u);
      if (r == ep * 16u - 1u)
        __hip_atomic_store(bar + 544, ep, __ATOMIC_RELAXED, __HIP_MEMORY_SCOPE_AGENT);
    }
    while (__hip_atomic_load(bar + 544, __ATOMIC_RELAXED, __HIP_MEMORY_SCOPE_AGENT) < ep)
      __builtin_amdgcn_s_sleep(1);
  }
  __syncthreads();
}

// ---- prologue helpers (R5-R7 verified, 256 blocks x 512 threads) ----------
template <int J, int N, int CPT>
__device__ void matmat(const float* __restrict__ A, const float* __restrict__ B,
                       float* __restrict__ C) {
  const int tid = threadIdx.x;
  const int r = blockIdx.x * 4 + (tid >> 7);
  const int c0 = tid & 127;
  float acc[CPT];
#pragma unroll
  for (int i = 0; i < CPT; ++i) acc[i] = 0.f;
  const float* ar = A + (size_t)r * J;
#pragma unroll 2
  for (int j = 0; j < J; ++j) {
    float av = ar[j];
    const float* br = B + (size_t)j * N + c0;
#pragma unroll
    for (int i = 0; i < CPT; ++i) acc[i] = fmaf(av, br[i * 128], acc[i]);
  }
  float* cr = C + (size_t)r * N + c0;
#pragma unroll
  for (int i = 0; i < CPT; ++i) cr[i * 128] = acc[i];
}

__device__ void vecmat(const float* __restrict__ v, const float* __restrict__ M,
                       const float* __restrict__ badd, float* __restrict__ outv,
                       int J, int N, int blk0, int nblk) {
  int b = (int)blockIdx.x;
  if (b < blk0 || b >= blk0 + nblk) return;
  int gid = (b - blk0) * 512 + threadIdx.x;
  if (gid >= N) return;
  float acc = 0.f;
#pragma unroll 4
  for (int j = 0; j < J; ++j) acc = fmaf(v[j], M[(size_t)j * N + gid], acc);
  outv[gid] = acc + badd[gid];
}

__device__ void gemv1024(const float* __restrict__ A, const float* __restrict__ W,
                         const float* __restrict__ bias, int K, int relu,
                         float* __restrict__ C, float* __restrict__ C2,
                         float* __restrict__ C3, float* red) {
  const int tid = threadIdx.x;
  const int m = tid & 63, w = tid >> 6;
  const int j = w & 3, hh = w >> 2;
  const int c = blockIdx.x * 4 + j;
  const int kh = K >> 1;
  const float* a = A + m + (hh * kh) * 64;
  const float* wp = W + c + (size_t)(hh * kh) * 1024;
  float acc = 0.f;
#pragma unroll 8
  for (int k = 0; k < kh; ++k) acc = fmaf(a[k * 64], wp[(size_t)k * 1024], acc);
  if (hh) red[j * 64 + m] = acc;
  __syncthreads();
  if (!hh) {
    float v = acc + red[j * 64 + m] + bias[c];
    if (relu) v = fmaxf(v, 0.f);
    C[c * 64 + m] = v;
    if (C2) C2[c * 64 + m] = v;
    if (C3) C3[c * 64 + m] = v;
  }
  __syncthreads();
}

// ---- GRU matmul: 256 blocks = 32 col-groups(96) x 8 K-slices(256) ---------
// s<4: x-part slice s; s>=4: h-part slice s-4. Wave w: m-half = w>>2,
// col-quarter = w&3; lane: p=lane>>5 picks 12-col subset, m = (w>>2)*32 +
// (lane&31). 12 acc/thread; act b32 is 2-way broadcast (free); weights 3x
// b128 (2 windows/wave). Acts staged sc1 -> LDS, double-buffered chunks.
__device__ __forceinline__ void gru_mm(const float* __restrict__ Wx,
                                       const float* __restrict__ actx,
                                       const float* __restrict__ Whm,
                                       const float* __restrict__ acth,
                                       float* __restrict__ part,
                                       float* __restrict__ sm) {
  float* sa = sm;            // [2][64*64]
  float* sw = sm + 8192;     // [2][64*96]
  const int tid = threadIdx.x;
  const int bid = blockIdx.x;
  const int g = bid >> 3, s = bid & 7;
  const int c0 = g * 96;
  const int k0 = (s & 3) * 256;
  const float* W = (s < 4 ? Wx : Whm);
  const float* A = (s < 4 ? actx : acth) + (size_t)k0 * 64;
  const int kr = tid >> 3, cs = (tid & 7) * 12;
  const int w = tid >> 6, lane = tid & 63;
  const int m = (w >> 2) * 32 + (lane & 31);
  const int cb = (w & 3) * 24 + (lane >> 5) * 12;

  float acc[12];
#pragma unroll
  for (int j = 0; j < 12; ++j) acc[j] = 0.f;
  unsigned long long av[4];
  float4 wl[3];
  {  // stage chunk 0
    const unsigned long long* Ab = (const unsigned long long*)A;
#pragma unroll
    for (int i = 0; i < 4; ++i) av[i] = ald64(Ab + tid + i * 512);
    const float* Wr = W + (size_t)(k0 + kr) * 3072 + c0 + cs;
    wl[0] = *(const float4*)Wr; wl[1] = *(const float4*)(Wr + 4);
    wl[2] = *(const float4*)(Wr + 8);
#pragma unroll
    for (int i = 0; i < 4; ++i) {
      int jj = tid + i * 512;
      *(unsigned long long*)(sa + ((jj >> 5) << 6) + ((jj & 31) << 1)) = av[i];
    }
    float* swr = sw + kr * 96 + cs;
    *(float4*)swr = wl[0]; *(float4*)(swr + 4) = wl[1]; *(float4*)(swr + 8) = wl[2];
  }
  for (int ch = 0; ch < 4; ++ch) {
    const int buf = ch & 1;
    __syncthreads();
    if (ch < 3) {
      const unsigned long long* Ab = (const unsigned long long*)(A + (ch + 1) * 4096);
#pragma unroll
      for (int i = 0; i < 4; ++i) av[i] = ald64(Ab + tid + i * 512);
      const float* Wr = W + (size_t)(k0 + (ch + 1) * 64 + kr) * 3072 + c0 + cs;
      wl[0] = *(const float4*)Wr; wl[1] = *(const float4*)(Wr + 4);
      wl[2] = *(const float4*)(Wr + 8);
    }
    const float* ap = sa + buf * 4096 + m;
    const float* wp = sw + buf * 6144 + cb;
#pragma unroll 8
    for (int k = 0; k < 64; ++k) {
      float a = ap[k * 64];
      float4 w0 = *(const float4*)(wp + k * 96);
      float4 w1 = *(const float4*)(wp + k * 96 + 4);
      float4 w2v = *(const float4*)(wp + k * 96 + 8);
      acc[0] = fmaf(a, w0.x, acc[0]);  acc[1] = fmaf(a, w0.y, acc[1]);
      acc[2] = fmaf(a, w0.z, acc[2]);  acc[3] = fmaf(a, w0.w, acc[3]);
      acc[4] = fmaf(a, w1.x, acc[4]);  acc[5] = fmaf(a, w1.y, acc[5]);
      acc[6] = fmaf(a, w1.z, acc[6]);  acc[7] = fmaf(a, w1.w, acc[7]);
      acc[8] = fmaf(a, w2v.x, acc[8]); acc[9] = fmaf(a, w2v.y, acc[9]);
      acc[10] = fmaf(a, w2v.z, acc[10]); acc[11] = fmaf(a, w2v.w, acc[11]);
    }
    if (ch < 3) {
      const int nb = buf ^ 1;
#pragma unroll
      for (int i = 0; i < 4; ++i) {
        int jj = tid + i * 512;
        *(unsigned long long*)(sa + nb * 4096 + ((jj >> 5) << 6) + ((jj & 31) << 1)) = av[i];
      }
      float* swr = sw + nb * 6144 + kr * 96 + cs;
      *(float4*)swr = wl[0]; *(float4*)(swr + 4) = wl[1]; *(float4*)(swr + 8) = wl[2];
    }
  }
  float* pb = part + ((size_t)s * 3072 + c0 + cb) * 64 + m;
#pragma unroll
  for (int j = 0; j < 12; ++j) ast(pb + (size_t)j * 64, acc[j]);
}

// GRU combine: 8 K-slices (0-3 x-part, 4-7 h-part). 256 blocks, 256 thr.
__device__ __forceinline__ void gru_comb(const float* __restrict__ part,
                                         const float* __restrict__ bx,
                                         const float* __restrict__ bm,
                                         float* __restrict__ h) {
  const int tid = threadIdx.x, bid = blockIdx.x;
  if (tid >= 256) return;
  const int c = bid * 4 + (tid >> 6), m = tid & 63;
  float ra = 0.f, za = 0.f, ia = 0.f, na = 0.f;
#pragma unroll
  for (int s = 0; s < 8; ++s) {
    const float* ps = part + (size_t)s * 3072 * 64;
    ra += ald(ps + (size_t)c * 64 + m);
    za += ald(ps + (size_t)(1024 + c) * 64 + m);
    float nv = ald(ps + (size_t)(2048 + c) * 64 + m);
    if (s < 4) ia += nv; else na += nv;
  }
  float r  = 1.f / (1.f + expf(-(ra + bx[c] + bm[c])));
  float zg = 1.f / (1.f + expf(-(za + bx[1024 + c] + bm[1024 + c])));
  float nn = tanhf(ia + bx[2048 + c] + r * (na + bm[2048 + c]));
  float hp = ald(h + (size_t)c * 64 + m);
  ast(h + (size_t)c * 64 + m, (1.f - zg) * nn + zg * hp);
}

// P5: C=1280 (1024 WhW1 | 256 Wh), 32 groups(40) x 8 K-slices(128).
// Wave w -> 5 cols at padded LDS slot w*8; lane = m.
__device__ __forceinline__ void p5_mm(const float* __restrict__ WhW1,
                                      const float* __restrict__ Wh,
                                      const float* __restrict__ h2,
                                      float* __restrict__ part,
                                      float* __restrict__ sm) {
  float* sa = sm;            // [2][4096]
  float* sw = sm + 8192;     // [2][4096] rows of 64 (8 waves x 8 slots)
  const int tid = threadIdx.x;
  const int bid = blockIdx.x;
  const int g = bid >> 3, s = bid & 7;
  const int c0 = g * 40;
  const int k0 = s * 128;
  const float* A = h2 + (size_t)k0 * 64;
  const int kr = tid >> 3, ci = (tid & 7) * 5;
  const int w = tid >> 6, lane = tid & 63;
  float acc[5] = {0.f, 0.f, 0.f, 0.f, 0.f};
  unsigned long long av[4];
  float wl[5];
#define P5LD(chk, jj) \
  ({ int gc = c0 + ci + (jj); int krow = k0 + (chk) * 64 + kr; \
     (gc < 1024) ? WhW1[(size_t)krow * 1024 + gc] : Wh[(size_t)krow * 256 + (gc - 1024)]; })
  {
    const unsigned long long* Ab = (const unsigned long long*)A;
#pragma unroll
    for (int i = 0; i < 4; ++i) av[i] = ald64(Ab + tid + i * 512);
#pragma unroll
    for (int jj = 0; jj < 5; ++jj) wl[jj] = P5LD(0, jj);
#pragma unroll
    for (int i = 0; i < 4; ++i) {
      int jj = tid + i * 512;
      *(unsigned long long*)(sa + ((jj >> 5) << 6) + ((jj & 31) << 1)) = av[i];
    }
#pragma unroll
    for (int jj = 0; jj < 5; ++jj) sw[kr * 64 + (tid & 7) * 8 + jj] = wl[jj];
  }
  for (int ch = 0; ch < 2; ++ch) {
    const int buf = ch & 1;
    __syncthreads();
    if (ch < 1) {
      const unsigned long long* Ab = (const unsigned long long*)(A + 4096);
#pragma unroll
      for (int i = 0; i < 4; ++i) av[i] = ald64(Ab + tid + i * 512);
#pragma unroll
      for (int jj = 0; jj < 5; ++jj) wl[jj] = P5LD(1, jj);
    }
    const float* ap = sa + buf * 4096 + lane;
    const float* wp = sw + buf * 4096 + w * 8;
#pragma unroll 8
    for (int k = 0; k < 64; ++k) {
      float a = ap[k * 64];
      float4 w4 = *(const float4*)(wp + k * 64);
      float w1v = wp[k * 64 + 4];
      acc[0] = fmaf(a, w4.x, acc[0]); acc[1] = fmaf(a, w4.y, acc[1]);
      acc[2] = fmaf(a, w4.z, acc[2]); acc[3] = fmaf(a, w4.w, acc[3]);
      acc[4] = fmaf(a, w1v, acc[4]);
    }
    if (ch < 1) {
#pragma unroll
      for (int i = 0; i < 4; ++i) {
        int jj = tid + i * 512;
        *(unsigned long long*)(sa + 4096 + ((jj >> 5) << 6) + ((jj & 31) << 1)) = av[i];
      }
#pragma unroll
      for (int jj = 0; jj < 5; ++jj) sw[4096 + kr * 64 + (tid & 7) * 8 + jj] = wl[jj];
    }
  }
#undef P5LD
  float* pb = part + ((size_t)s * 1280 + c0 + w * 5) * 64 + lane;
#pragma unroll
  for (int j = 0; j < 5; ++j) ast(pb + (size_t)j * 64, acc[j]);
}

// P5 combine: t1 cols 0..1023 (tid<256), out cols 1024..1279 (tid 256..319).
__device__ __forceinline__ void p5b(const float* __restrict__ part,
                                    const float* __restrict__ bhw1,
                                    const float* __restrict__ bh,
                                    float* __restrict__ t1, float* __restrict__ out,
                                    int t) {
  const int tid = threadIdx.x, bid = blockIdx.x;
  if (tid < 256) {
    const int c = bid * 4 + (tid >> 6), m = tid & 63;
    float v = 0.f;
#pragma unroll
    for (int s = 0; s < 8; ++s) v += ald(part + ((size_t)s * 1280 + c) * 64 + m);
    ast(t1 + (size_t)c * 64 + m, fmaxf(v + bhw1[c], 0.f));
  } else if (tid < 320) {
    const int m = tid - 256, c2 = bid;
    float v = 0.f;
#pragma unroll
    for (int s = 0; s < 8; ++s) v += ald(part + ((size_t)s * 1280 + 1024 + c2) * 64 + m);
    out[(size_t)(m * TSTEP + t) * LATD + c2] = v + bh[c2];
  }
}

// P6: C=1024, 32 groups(32) x 8 K-slices(128). Wave w -> 4 cols (b128).
__device__ __forceinline__ void p6_mm(const float* __restrict__ w2,
                                      const float* __restrict__ t1,
                                      float* __restrict__ part,
                                      float* __restrict__ sm) {
  float* sa = sm;            // [2][4096]
  float* sw = sm + 8192;     // [2][2048] rows of 32
  const int tid = threadIdx.x;
  const int bid = blockIdx.x;
  const int g = bid >> 3, s = bid & 7;
  const int c0 = g * 32;
  const int k0 = s * 128;
  const float* A = t1 + (size_t)k0 * 64;
  const int kr = tid >> 3, ci = (tid & 7) * 4;
  const int w = tid >> 6, lane = tid & 63;
  float acc[4] = {0.f, 0.f, 0.f, 0.f};
  unsigned long long av[4];
  float4 wl;
  {
    const unsigned long long* Ab = (const unsigned long long*)A;
#pragma unroll
    for (int i = 0; i < 4; ++i) av[i] = ald64(Ab + tid + i * 512);
    wl = *(const float4*)(w2 + (size_t)(k0 + kr) * 1024 + c0 + ci);
#pragma unroll
    for (int i = 0; i < 4; ++i) {
      int jj = tid + i * 512;
      *(unsigned long long*)(sa + ((jj >> 5) << 6) + ((jj & 31) << 1)) = av[i];
    }
    *(float4*)(sw + kr * 32 + ci) = wl;
  }
  for (int ch = 0; ch < 2; ++ch) {
    const int buf = ch & 1;
    __syncthreads();
    if (ch < 1) {
      const unsigned long long* Ab = (const unsigned long long*)(A + 4096);
#pragma unroll
      for (int i = 0; i < 4; ++i) av[i] = ald64(Ab + tid + i * 512);
      wl = *(const float4*)(w2 + (size_t)(k0 + 64 + kr) * 1024 + c0 + ci);
    }
    const float* ap = sa + buf * 4096 + lane;
    const float* wp = sw + buf * 2048 + w * 4;
#pragma unroll 8
    for (int k = 0; k < 64; ++k) {
      float a = ap[k * 64];
      float4 w4 = *(const float4*)(wp + k * 32);
      acc[0] = fmaf(a, w4.x, acc[0]); acc[1] = fmaf(a, w4.y, acc[1]);
      acc[2] = fmaf(a, w4.z, acc[2]); acc[3] = fmaf(a, w4.w, acc[3]);
    }
    if (ch < 1) {
#pragma unroll
      for (int i = 0; i < 4; ++i) {
        int jj = tid + i * 512;
        *(unsigned long long*)(sa + 4096 + ((jj >> 5) << 6) + ((jj & 31) << 1)) = av[i];
      }
      *(float4*)(sw + 2048 + kr * 32 + ci) = wl;
    }
  }
  float* pb = part + ((size_t)s * 1024 + c0 + w * 4) * 64 + lane;
#pragma unroll
  for (int j = 0; j < 4; ++j) ast(pb + (size_t)j * 64, acc[j]);
}

__device__ __forceinline__ void p6b(const float* __restrict__ part,
                                    const float* __restrict__ b2,
                                    float* __restrict__ gin) {
  const int tid = threadIdx.x, bid = blockIdx.x;
  if (tid >= 256) return;
  const int c = bid * 4 + (tid >> 6), m = tid & 63;
  float v = 0.f;
#pragma unroll
  for (int s = 0; s < 8; ++s) v += ald(part + ((size_t)s * 1024 + c) * 64 + m);
  ast(gin + (size_t)c * 64 + m, fmaxf(v + b2[c], 0.f));
}

__global__ __launch_bounds__(512, 1) void persist(P p) {
  cg::grid_group grid = cg::this_grid();
  __shared__ float sm[20480];   // 80 KB: [acts 2x4096 | weights 2x6144]
  unsigned ep = 0;

  // ---- prologue (4 slow cg syncs; their fences flush prologue's normal
  //      stores so loop-side cached weight reads + sc1 act reads start clean)
  if (blockIdx.x == 0) {
    for (int i = threadIdx.x; i < 1024; i += 512) p.bar[i] = 0u;
  }
  if (threadIdx.x < 64) {  // z transpose -> h1 region (consumed pre-overwrite)
    int i = blockIdx.x * 64 + threadIdx.x;
    int m = i >> 8, l = i & 255;
    p.h1[l * 64 + m] = p.z[i];
  }
  matmat<1024, 1024, 8>(p.Wv, p.Wo, p.part);            // Wvo
  vecmat(p.bh, p.w1, p.b1, p.bhw1, 256, 1024, 0, 2);
  vecmat(p.bv, p.Wo, p.bo, p.bvo, 1024, 1024, 2, 2);
  grid.sync();
  matmat<1024, 3072, 24>(p.part, p.Wih0, p.Wvoih);      // Wvoih = Wvo@Wih0
  matmat<256, 1024, 8>(p.Wh, p.w1, p.WhW1);             // WhW1 = Wh@w1
  vecmat(p.bvo, p.Wih0, p.bih0, p.bfold, 1024, 3072, 0, 6);
  grid.sync();
  gemv1024(p.h1, p.w1, p.b1, 256, 1, p.t1, nullptr, nullptr, sm);
  grid.sync();
  gemv1024(p.t1, p.w2, p.b2, 1024, 0, p.h1, p.h2, p.gin, sm);
  grid.sync();

  // ---- time loop: 8 fence-free phases/step ----
  for (int t = 0; t < TSTEP; ++t) {
    gru_mm(p.Wvoih, p.gin, p.Whh0, p.h1, p.part, sm);   fastbar(p.bar, ep);
    gru_comb(p.part, p.bfold, p.bhh0, p.h1);            fastbar(p.bar, ep);
    gru_mm(p.Wih1, p.h1, p.Whh1, p.h2, p.part, sm);     fastbar(p.bar, ep);
    gru_comb(p.part, p.bih1, p.bhh1, p.h2);             fastbar(p.bar, ep);
    p5_mm(p.WhW1, p.Wh, p.h2, p.part, sm);              fastbar(p.bar, ep);
    p5b(p.part, p.bhw1, p.bh, p.t1, p.out, t);          fastbar(p.bar, ep);
    p6_mm(p.w2, p.t1, p.part, sm);                      fastbar(p.bar, ep);
    p6b(p.part, p.b2, p.gin);                           fastbar(p.bar, ep);
  }
}

// ---------------------------------------------------------------------------
// Fallback path (round-2 verified multi-kernel).
// ---------------------------------------------------------------------------
__global__ void fb_transpose(const float* __restrict__ z, float* __restrict__ zT) {
  int i = blockIdx.x * 256 + threadIdx.x;
  int m = i >> 8, l = i & 255;
  zT[l * 64 + m] = z[i];
}
__global__ void fb_copy2(const float* __restrict__ s, float* __restrict__ d1,
                         float* __restrict__ d2) {
  int i = blockIdx.x * 256 + threadIdx.x;
  float v = s[i]; d1[i] = v; d2[i] = v;
}
template <int ACT>
__global__ void fb_gemm(const float* __restrict__ A_T, const float* __restrict__ W,
                        const float* __restrict__ bias, float* __restrict__ C_T,
                        int K, int N, float* __restrict__ outp, int tstep) {
  const int m = threadIdx.x & 63;
  const int wv = threadIdx.x >> 6;
  const int c = blockIdx.x * 4 + wv;
  float acc0 = 0.f, acc1 = 0.f;
  const float* ap = A_T + m;
  const float* wp = W + c;
#pragma unroll 4
  for (int k = 0; k + 1 < K; k += 2) {
    acc0 = fmaf(ap[k * 64], wp[(size_t)k * N], acc0);
    acc1 = fmaf(ap[(k + 1) * 64], wp[(size_t)(k + 1) * N], acc1);
  }
  float v0 = acc0 + acc1 + bias[c];
  if (ACT) v0 = fmaxf(v0, 0.f);
  C_T[c * 64 + m] = v0;
  if (outp != nullptr) outp[(size_t)(m * TSTEP + tstep) * LATD + c] = v0;
}
__global__ void fb_gru(const float* __restrict__ xT, const float* __restrict__ hT,
                       const float* __restrict__ Wih, const float* __restrict__ Whh,
                       const float* __restrict__ bih, const float* __restrict__ bhh,
                       float* __restrict__ hnT) {
  const int m = threadIdx.x & 63;
  const int wv = threadIdx.x >> 6;
  const int c = blockIdx.x * 4 + wv;
  float racc = 0, zacc = 0, iacc = 0, nacc = 0;
  const float* xp = xT + m;
  const float* hp = hT + m;
  const float* wi = Wih + c;
  const float* wh = Whh + c;
#pragma unroll 2
  for (int k = 0; k < 1024; ++k) {
    float a = xp[k * 64];
    float h = hp[k * 64];
    const float* wik = wi + (size_t)k * 3072;
    const float* whk = wh + (size_t)k * 3072;
    racc = fmaf(a, wik[0], racc); racc = fmaf(h, whk[0], racc);
    zacc = fmaf(a, wik[1024], zacc); zacc = fmaf(h, whk[1024], zacc);
    iacc = fmaf(a, wik[2048], iacc);
    nacc = fmaf(h, whk[2048], nacc);
  }
  float r = 1.f / (1.f + expf(-(racc + bih[c] + bhh[c])));
  float zg = 1.f / (1.f + expf(-(zacc + bih[1024 + c] + bhh[1024 + c])));
  float nn = tanhf(iacc + bih[2048 + c] + r * (nacc + bhh[2048 + c]));
  hnT[c * 64 + m] = (1.f - zg) * nn + zg * hT[c * 64 + m];
}

extern "C" void kernel_launch(void* const* d_in, const int* in_sizes, int n_in,
                              void* d_out, int out_size, void* d_ws, size_t ws_size,
                              hipStream_t stream) {
  const float* z_start = (const float*)d_in[0];
  const float* w1 = (const float*)d_in[2];
  const float* b1 = (const float*)d_in[3];
  const float* w2 = (const float*)d_in[4];
  const float* b2 = (const float*)d_in[5];
  const float* Wv = (const float*)d_in[10];
  const float* bv = (const float*)d_in[11];
  const float* Wo = (const float*)d_in[12];
  const float* bo = (const float*)d_in[13];
  const float* Wih0 = (const float*)d_in[14];
  const float* Whh0 = (const float*)d_in[15];
  const float* bih0 = (const float*)d_in[16];
  const float* bhh0 = (const float*)d_in[17];
  const float* Wih1 = (const float*)d_in[18];
  const float* Whh1 = (const float*)d_in[19];
  const float* bih1 = (const float*)d_in[20];
  const float* bhh1 = (const float*)d_in[21];
  const float* Wh = (const float*)d_in[22];
  const float* bh = (const float*)d_in[23];
  float* out = (float*)d_out;
  float* ws = (float*)d_ws;

  // floats: Wvoih 3145728 + WhW1 1048576 + part 1572864 + gin/h1/h2/t1
  //         4x65536 + bvo 1024 + bfold 3072 + bhw1 1024 + bar 1024
  const size_t need = (size_t)(3145728 + 1048576 + 1572864 + 262144 + 5120 + 1024) * 4;
  if (ws_size >= need) {
    P p;
    p.z = z_start; p.w1 = w1; p.b1 = b1; p.w2 = w2; p.b2 = b2;
    p.Wv = Wv; p.bv = bv; p.Wo = Wo; p.bo = bo;
    p.Wih0 = Wih0; p.Whh0 = Whh0; p.bih0 = bih0; p.bhh0 = bhh0;
    p.Wih1 = Wih1; p.Whh1 = Whh1; p.bih1 = bih1; p.bhh1 = bhh1;
    p.Wh = Wh; p.bh = bh; p.out = out;
    float* q = ws;
    p.Wvoih = q; q += 3145728;
    p.WhW1 = q; q += 1048576;
    p.part = q; q += 1572864;   // Wvo in prologue; phase partials in loop
    p.gin = q; q += 65536;
    p.h1 = q; q += 65536;       // also zT during prologue
    p.h2 = q; q += 65536;
    p.t1 = q; q += 65536;
    p.bvo = q; q += 1024;
    p.bfold = q; q += 3072;
    p.bhw1 = q; q += 1024;
    p.bar = (unsigned*)q; q += 1024;
    void* args[] = { &p };
    hipError_t e = hipLaunchCooperativeKernel((const void*)persist, dim3(256),
                                              dim3(512), args, 0, stream);
    if (e == hipSuccess) return;
  }

  // -------- fallback: verified round-2 path --------
  float* zsT = ws;
  float* vT = zsT + 16384;
  float* xaT = vT + 65536;
  float* t1T = xaT + 65536;
  float* ginT = t1T + 65536;
  float* nzT = ginT + 65536;
  float* h1T = nzT + 16384;
  float* h2T = h1T + 2 * 65536;

  fb_transpose<<<64, 256, 0, stream>>>(z_start, zsT);
  fb_gemm<1><<<256, 256, 0, stream>>>(zsT, w1, b1, t1T, 256, 1024, nullptr, 0);
  fb_gemm<0><<<256, 256, 0, stream>>>(t1T, w2, b2, h1T, 1024, 1024, nullptr, 0);
  fb_copy2<<<256, 256, 0, stream>>>(h1T, h2T, ginT);
  for (int t = 0; t < TSTEP; ++t) {
    float* h1p = h1T + (t & 1) * 65536;
    float* h1n = h1T + ((t + 1) & 1) * 65536;
    float* h2p = h2T + (t & 1) * 65536;
    float* h2n = h2T + ((t + 1) & 1) * 65536;
    fb_gemm<0><<<256, 256, 0, stream>>>(ginT, Wv, bv, vT, 1024, 1024, nullptr, 0);
    fb_gemm<0><<<256, 256, 0, stream>>>(vT, Wo, bo, xaT, 1024, 1024, nullptr, 0);
    fb_gru<<<256, 256, 0, stream>>>(xaT, h1p, Wih0, Whh0, bih0, bhh0, h1n);
    fb_gru<<<256, 256, 0, stream>>>(h1n, h2p, Wih1, Whh1, bih1, bhh1, h2n);
    fb_gemm<0><<<64, 256, 0, stream>>>(h2n, Wh, bh, nzT, 1024, 256, out, t);
    fb_gemm<1><<<256, 256, 0, stream>>>(nzT, w1, b1, t1T, 256, 1024, nullptr, 0);
    fb_gemm<1><<<256, 256, 0, stream>>>(t1T, w2, b2, ginT, 1024, 1024, nullptr, 0);
  }
}